// Round 2
// baseline (448.074 us; speedup 1.0000x reference)
//
#include <hip/hip_runtime.h>
#include <hip/hip_bf16.h>

#define B_ 512
#define E_ 1024
#define N_ 1024
#define M_ 128
#define P_ 134   // M+6

__device__ __forceinline__ float softplus_f(float x) {
    // stable: max(x,0) + log1p(exp(-|x|))  (matches jax.nn.softplus)
    return fmaxf(x, 0.f) + log1pf(expf(-fabsf(x)));
}

// ---------------- K1: params = emb @ W + b; derive k, |k|, beta, g, s, y ----
// one block per b; threads 0..133 each own one output column, 4-way unrolled
// accumulators break the dependent-FMA chain (4096-cyc serial floor -> ~1k).
__global__ __launch_bounds__(256) void k_params(
    const float* __restrict__ emb, const float* __restrict__ W,
    const float* __restrict__ bias,
    float* __restrict__ k_all, float* __restrict__ knorm,
    float* __restrict__ scal)
{
    __shared__ float se[E_];
    __shared__ float sp[P_];
    __shared__ float red[2];
    const int b = blockIdx.x, t = threadIdx.x;
    for (int i = t; i < E_; i += 256) se[i] = emb[b * E_ + i];
    __syncthreads();
    if (t < P_) {
        float a0 = 0.f, a1 = 0.f, a2 = 0.f, a3 = 0.f;
        #pragma unroll 4
        for (int e = 0; e < E_; e += 4) {
            a0 = fmaf(se[e + 0], W[(e + 0) * P_ + t], a0);
            a1 = fmaf(se[e + 1], W[(e + 1) * P_ + t], a1);
            a2 = fmaf(se[e + 2], W[(e + 2) * P_ + t], a2);
            a3 = fmaf(se[e + 3], W[(e + 3) * P_ + t], a3);
        }
        sp[t] = bias[t] + ((a0 + a1) + (a2 + a3));
    }
    __syncthreads();
    // ||k||^2 : wave 0 (lanes 0..63) reduces 128 elements
    if (t < 64) {
        float v = sp[t] * sp[t] + sp[t + 64] * sp[t + 64];
        #pragma unroll
        for (int m = 1; m < 64; m <<= 1) v += __shfl_xor(v, m);
        if (t == 0) red[0] = v;
    }
    __syncthreads();
    if (t < M_) k_all[b * M_ + t] = sp[t];
    if (t == 0) {
        knorm[b] = sqrtf(red[0]);
        float beta = softplus_f(sp[M_ + 0]);
        float g    = 1.f / (1.f + expf(-sp[M_ + 1]));
        float a0 = sp[M_ + 2], a1 = sp[M_ + 3], a2 = sp[M_ + 4];
        float mx = fmaxf(a0, fmaxf(a1, a2));
        float e0 = expf(a0 - mx), e1 = expf(a1 - mx), e2 = expf(a2 - mx);
        float inv = 1.f / (e0 + e1 + e2);
        float y = 1.f + softplus_f(sp[M_ + 5]);
        float* sc = &scal[b * 8];
        sc[0] = beta; sc[1] = g; sc[2] = e0 * inv; sc[3] = e1 * inv;
        sc[4] = e2 * inv; sc[5] = y;
    }
}

// ---------------- K2: z[b,n] = beta * cos(k, memory[b,n]) -------------------
// one wave handles 32 consecutive rows (processed as 16 row-pairs);
// lane loads float4 -> wave reads 1024B contiguous per iteration.
__global__ __launch_bounds__(256) void k_cos(
    const float* __restrict__ mem, const float* __restrict__ k_all,
    const float* __restrict__ knorm, const float* __restrict__ scal,
    float* __restrict__ z)
{
    const int wid  = blockIdx.x * 4 + (threadIdx.x >> 6);   // 16384 waves
    const int lane = threadIdx.x & 63;
    const int b    = wid >> 5;                              // 32 waves per b
    const int n0   = (wid & 31) * 32;
    const int half = lane >> 5, q = lane & 31;
    const float4 k4   = *(const float4*)&k_all[b * M_ + q * 4];
    const float  kn   = knorm[b];
    const float  beta = scal[b * 8];
    const float* base = mem + ((size_t)b * N_ + n0 + half) * M_ + q * 4;
    float* zb = z + b * N_ + n0 + half;
    #pragma unroll 4
    for (int i = 0; i < 16; ++i) {
        const float4 v = *(const float4*)(base + (size_t)i * 2 * M_);
        float dot = v.x * k4.x + v.y * k4.y + v.z * k4.z + v.w * k4.w;
        float sq  = v.x * v.x + v.y * v.y + v.z * v.z + v.w * v.w;
        #pragma unroll
        for (int m = 1; m < 32; m <<= 1) {
            dot += __shfl_xor(dot, m);
            sq  += __shfl_xor(sq,  m);
        }
        if (q == 0) {
            float mn = sqrtf(sq);
            zb[i * 2] = beta * dot / (kn * mn + 1e-16f);
        }
    }
}

// ---------------- K3: softmax over N + gate + shift + pow + renorm ----------
__device__ __forceinline__ float block_sum(float v, volatile float* red, int t) {
    #pragma unroll
    for (int m = 1; m < 64; m <<= 1) v += __shfl_xor(v, m);
    __syncthreads();
    if ((t & 63) == 0) red[t >> 6] = v;
    __syncthreads();
    return red[0] + red[1] + red[2] + red[3];
}
__device__ __forceinline__ float block_max(float v, volatile float* red, int t) {
    #pragma unroll
    for (int m = 1; m < 64; m <<= 1) v = fmaxf(v, __shfl_xor(v, m));
    __syncthreads();
    if ((t & 63) == 0) red[t >> 6] = v;
    __syncthreads();
    return fmaxf(fmaxf(red[0], red[1]), fmaxf(red[2], red[3]));
}

__global__ __launch_bounds__(256) void k_weights(
    const float* __restrict__ z_in, const float* __restrict__ w_prev,
    const float* __restrict__ scal, float* __restrict__ w_out)
{
    __shared__ float wg[N_];
    __shared__ float red[4];
    const int b = blockIdx.x, t = threadIdx.x;
    const float g  = scal[b * 8 + 1];
    const float s0 = scal[b * 8 + 2], s1 = scal[b * 8 + 3], s2 = scal[b * 8 + 4];
    const float y  = scal[b * 8 + 5];
    float zv[4];
    float mx = -INFINITY;
    #pragma unroll
    for (int j = 0; j < 4; ++j) {
        zv[j] = z_in[b * N_ + t * 4 + j];
        mx = fmaxf(mx, zv[j]);
    }
    mx = block_max(mx, red, t);
    float lsum = 0.f, ev[4];
    #pragma unroll
    for (int j = 0; j < 4; ++j) { ev[j] = expf(zv[j] - mx); lsum += ev[j]; }
    float inv = 1.f / block_sum(lsum, red, t);
    #pragma unroll
    for (int j = 0; j < 4; ++j) {
        float wc = ev[j] * inv;
        wg[t * 4 + j] = g * wc + (1.f - g) * w_prev[b * N_ + t * 4 + j];
    }
    __syncthreads();
    float wp[4], psum = 0.f;
    #pragma unroll
    for (int j = 0; j < 4; ++j) {
        int n = t * 4 + j;
        float wt = s0 * wg[(n - 1) & (N_ - 1)] + s1 * wg[n] + s2 * wg[(n + 1) & (N_ - 1)];
        wp[j] = powf(wt + 1e-16f, y);
        psum += wp[j];
    }
    float pinv = 1.f / block_sum(psum, red, t);
    #pragma unroll
    for (int j = 0; j < 4; ++j) w_out[b * N_ + t * 4 + j] = wp[j] * pinv;
}

// ---------------- K4: memory_data[b,:] = sum_n w[b,n] * memory[b,n,:] -------
// one block per b: 1024 thr = 32 row-lanes x 32 float4-lanes; LDS tree reduce,
// single store, no atomics, no output pre-zeroing needed.
__global__ __launch_bounds__(1024) void k_read(
    const float* __restrict__ mem, const float* __restrict__ w,
    float* __restrict__ out)
{
    __shared__ float4 lds[32][32];
    const int b = blockIdx.x;
    const int t = threadIdx.x;
    const int r = t >> 5, q = t & 31;
    float4 acc = make_float4(0.f, 0.f, 0.f, 0.f);
    const float* base = mem + ((size_t)b * N_ + r) * M_ + q * 4;
    const float* wb = w + b * N_ + r;
    #pragma unroll 4
    for (int i = 0; i < 32; ++i) {
        float wv = wb[i * 32];
        const float4 v = *(const float4*)(base + (size_t)i * 32 * M_);
        acc.x = fmaf(wv, v.x, acc.x);
        acc.y = fmaf(wv, v.y, acc.y);
        acc.z = fmaf(wv, v.z, acc.z);
        acc.w = fmaf(wv, v.w, acc.w);
    }
    lds[r][q] = acc;
    __syncthreads();
    #pragma unroll
    for (int s = 16; s > 0; s >>= 1) {
        if (r < s) {
            float4 u = lds[r + s][q];
            float4 m = lds[r][q];
            m.x += u.x; m.y += u.y; m.z += u.z; m.w += u.w;
            lds[r][q] = m;
        }
        __syncthreads();
    }
    if (r == 0) {
        float4 s0 = lds[0][q];
        *(float4*)&out[b * M_ + q * 4] = s0;
    }
}

extern "C" void kernel_launch(void* const* d_in, const int* in_sizes, int n_in,
                              void* d_out, int out_size, void* d_ws, size_t ws_size,
                              hipStream_t stream) {
    const float* emb    = (const float*)d_in[0];
    const float* w_prev = (const float*)d_in[1];
    const float* mem    = (const float*)d_in[2];
    const float* W      = (const float*)d_in[3];
    const float* bias   = (const float*)d_in[4];

    float* out_md = (float*)d_out;               // (512,128) memory_data
    float* out_w  = (float*)d_out + B_ * M_;     // (512,1024) w (z staged here)

    float* ws    = (float*)d_ws;
    float* k_all = ws;                 // 512*128 = 65536
    float* knorm = ws + 65536;         // 512
    float* scal  = ws + 66048;         // 512*8 = 4096

    k_params <<<B_, 256, 0, stream>>>(emb, W, bias, k_all, knorm, scal);
    k_cos    <<<4096, 256, 0, stream>>>(mem, k_all, knorm, scal, out_w);
    k_weights<<<B_, 256, 0, stream>>>(out_w, w_prev, scal, out_w);
    k_read   <<<B_, 1024, 0, stream>>>(mem, out_w, out_md);
}

// Round 5
// 427.271 us; speedup vs baseline: 1.0487x; 1.0487x over previous
//
#include <hip/hip_runtime.h>
#include <hip/hip_bf16.h>

#define B_ 512
#define E_ 1024
#define N_ 1024
#define M_ 128
#define P_ 134   // M+6

#define RLO 24   // pass-1 iters [24,32): register cache (8 float4/thread)
#define LLO 18   // pass-1 iters [18,24): LDS cache (6 x 16KB = 96KB)

__device__ __forceinline__ float softplus_f(float x) {
    return fmaxf(x, 0.f) + log1pf(expf(-fabsf(x)));
}

// ---------------- K1: params = emb @ W + b; derive k, |k|, beta, g, s, y ----
// (validated in the round-2 passing bench)
__global__ __launch_bounds__(256) void k_params(
    const float* __restrict__ emb, const float* __restrict__ W,
    const float* __restrict__ bias,
    float* __restrict__ k_all, float* __restrict__ knorm,
    float* __restrict__ scal)
{
    __shared__ float se[E_];
    __shared__ float sp[P_];
    __shared__ float red[2];
    const int b = blockIdx.x, t = threadIdx.x;
    for (int i = t; i < E_; i += 256) se[i] = emb[b * E_ + i];
    __syncthreads();
    if (t < P_) {
        float a0 = 0.f, a1 = 0.f, a2 = 0.f, a3 = 0.f;
        #pragma unroll 4
        for (int e = 0; e < E_; e += 4) {
            a0 = fmaf(se[e + 0], W[(e + 0) * P_ + t], a0);
            a1 = fmaf(se[e + 1], W[(e + 1) * P_ + t], a1);
            a2 = fmaf(se[e + 2], W[(e + 2) * P_ + t], a2);
            a3 = fmaf(se[e + 3], W[(e + 3) * P_ + t], a3);
        }
        sp[t] = bias[t] + ((a0 + a1) + (a2 + a3));
    }
    __syncthreads();
    if (t < 64) {
        float v = sp[t] * sp[t] + sp[t + 64] * sp[t + 64];
        #pragma unroll
        for (int m = 1; m < 64; m <<= 1) v += __shfl_xor(v, m);
        if (t == 0) red[0] = v;
    }
    __syncthreads();
    if (t < M_) k_all[b * M_ + t] = sp[t];
    if (t == 0) {
        knorm[b] = sqrtf(red[0]);
        float beta = softplus_f(sp[M_ + 0]);
        float g    = 1.f / (1.f + expf(-sp[M_ + 1]));
        float a0 = sp[M_ + 2], a1 = sp[M_ + 3], a2 = sp[M_ + 4];
        float mx = fmaxf(a0, fmaxf(a1, a2));
        float e0 = expf(a0 - mx), e1 = expf(a1 - mx), e2 = expf(a2 - mx);
        float inv = 1.f / (e0 + e1 + e2);
        float y = 1.f + softplus_f(sp[M_ + 5]);
        float* sc = &scal[b * 8];
        sc[0] = beta; sc[1] = g; sc[2] = e0 * inv; sc[3] = e1 * inv;
        sc[4] = e2 * inv; sc[5] = y;
    }
}

// ---------------- KF: fused cos + softmax/gate/shift/pow + weighted read ----
// One block per b (1024 thr = 16 waves). 112KB LDS forces 1 block/CU so the
// GPU-resident fresh set (256 x 512KB = 128MB) fits L3. Tile tail cached:
// iters 24..31 in registers, 18..23 in LDS; iters 0..17 re-read (L3 hits).
__global__ __launch_bounds__(1024) void k_fused(
    const float* __restrict__ mem, const float* __restrict__ w_prev,
    const float* __restrict__ k_all, const float* __restrict__ knorm,
    const float* __restrict__ scal,
    float* __restrict__ out_md, float* __restrict__ out_w)
{
    __shared__ float zbuf[N_];           // z, later final w
    __shared__ float wgbuf[N_];          // gated weights (neighbor access)
    __shared__ float red[16];
    __shared__ float4 acc16[16][32];
    __shared__ float cache[6][32][M_];   // 96 KB tile cache

    const int b    = blockIdx.x;
    const int t    = threadIdx.x;
    const int wid  = t >> 6;
    const int lane = t & 63;
    const int half = lane >> 5, q = lane & 31;

    const float4 k4   = *(const float4*)&k_all[b * M_ + q * 4];
    const float  kn   = knorm[b];
    const float  beta = scal[b * 8 + 0];
    const float  g    = scal[b * 8 + 1];
    const float  s0   = scal[b * 8 + 2];
    const float  s1   = scal[b * 8 + 3];
    const float  s2   = scal[b * 8 + 4];
    const float  y    = scal[b * 8 + 5];

    const float* base = mem + ((size_t)b * N_ + wid * 64 + half) * M_ + q * 4;
    float4 rc[8];

    // ---- pass 1a: stream iters 0..17 ----
    #pragma unroll 6
    for (int i = 0; i < LLO; ++i) {
        const float4 v = *(const float4*)(base + (size_t)i * 2 * M_);
        float dot = v.x * k4.x + v.y * k4.y + v.z * k4.z + v.w * k4.w;
        float sq  = v.x * v.x + v.y * v.y + v.z * v.z + v.w * v.w;
        #pragma unroll
        for (int m = 1; m < 32; m <<= 1) {
            dot += __shfl_xor(dot, m);
            sq  += __shfl_xor(sq,  m);
        }
        if (q == 0)
            zbuf[wid * 64 + 2 * i + half] = beta * dot / (kn * sqrtf(sq) + 1e-16f);
    }
    // ---- pass 1b: iters 18..23, LDS-cached ----
    #pragma unroll
    for (int i = LLO; i < RLO; ++i) {
        const float4 v = *(const float4*)(base + (size_t)i * 2 * M_);
        *(float4*)&cache[i - LLO][wid * 2 + half][q * 4] = v;
        float dot = v.x * k4.x + v.y * k4.y + v.z * k4.z + v.w * k4.w;
        float sq  = v.x * v.x + v.y * v.y + v.z * v.z + v.w * v.w;
        #pragma unroll
        for (int m = 1; m < 32; m <<= 1) {
            dot += __shfl_xor(dot, m);
            sq  += __shfl_xor(sq,  m);
        }
        if (q == 0)
            zbuf[wid * 64 + 2 * i + half] = beta * dot / (kn * sqrtf(sq) + 1e-16f);
    }
    // ---- pass 1c: iters 24..31, register-cached (static indices) ----
    #pragma unroll
    for (int ii = 0; ii < 8; ++ii) {
        const int i = RLO + ii;
        const float4 v = *(const float4*)(base + (size_t)i * 2 * M_);
        rc[ii] = v;
        float dot = v.x * k4.x + v.y * k4.y + v.z * k4.z + v.w * k4.w;
        float sq  = v.x * v.x + v.y * v.y + v.z * v.z + v.w * v.w;
        #pragma unroll
        for (int m = 1; m < 32; m <<= 1) {
            dot += __shfl_xor(dot, m);
            sq  += __shfl_xor(sq,  m);
        }
        if (q == 0)
            zbuf[wid * 64 + 2 * i + half] = beta * dot / (kn * sqrtf(sq) + 1e-16f);
    }
    __syncthreads();

    // ---- phase B: softmax over N + gate + shift + pow + renorm ----
    float zv = zbuf[t];
    float v = zv;
    #pragma unroll
    for (int m = 1; m < 64; m <<= 1) v = fmaxf(v, __shfl_xor(v, m));
    if (lane == 0) red[wid] = v;
    __syncthreads();
    float mx = red[0];
    #pragma unroll
    for (int j = 1; j < 16; ++j) mx = fmaxf(mx, red[j]);
    float ev = expf(zv - mx);
    v = ev;
    #pragma unroll
    for (int m = 1; m < 64; m <<= 1) v += __shfl_xor(v, m);
    __syncthreads();
    if (lane == 0) red[wid] = v;
    __syncthreads();
    float esum = 0.f;
    #pragma unroll
    for (int j = 0; j < 16; ++j) esum += red[j];
    float wc = ev / esum;
    wgbuf[t] = g * wc + (1.f - g) * w_prev[b * N_ + t];
    __syncthreads();
    float wt = s0 * wgbuf[(t - 1) & (N_ - 1)] + s1 * wgbuf[t] + s2 * wgbuf[(t + 1) & (N_ - 1)];
    float wp = powf(wt + 1e-16f, y);
    v = wp;
    #pragma unroll
    for (int m = 1; m < 64; m <<= 1) v += __shfl_xor(v, m);
    __syncthreads();
    if (lane == 0) red[wid] = v;
    __syncthreads();
    float psum = 0.f;
    #pragma unroll
    for (int j = 0; j < 16; ++j) psum += red[j];
    float wfin = wp / psum;
    zbuf[t] = wfin;                       // zbuf now holds final w
    out_w[b * N_ + t] = wfin;
    __syncthreads();

    // ---- pass 2: out_md[b,:] = sum_n w[n] * mem[b,n,:] ----
    float4 acc = make_float4(0.f, 0.f, 0.f, 0.f);
    #pragma unroll
    for (int ii = 7; ii >= 0; --ii) {             // register-cached iters
        float wv = zbuf[wid * 64 + 2 * (RLO + ii) + half];
        acc.x = fmaf(wv, rc[ii].x, acc.x);
        acc.y = fmaf(wv, rc[ii].y, acc.y);
        acc.z = fmaf(wv, rc[ii].z, acc.z);
        acc.w = fmaf(wv, rc[ii].w, acc.w);
    }
    #pragma unroll
    for (int i = RLO - 1; i >= LLO; --i) {        // LDS-cached iters
        float wv = zbuf[wid * 64 + 2 * i + half];
        const float4 mv = *(const float4*)&cache[i - LLO][wid * 2 + half][q * 4];
        acc.x = fmaf(wv, mv.x, acc.x);
        acc.y = fmaf(wv, mv.y, acc.y);
        acc.z = fmaf(wv, mv.z, acc.z);
        acc.w = fmaf(wv, mv.w, acc.w);
    }
    #pragma unroll 6
    for (int i = LLO - 1; i >= 0; --i) {          // re-read (L3-resident)
        float wv = zbuf[wid * 64 + 2 * i + half];
        const float4 mv = *(const float4*)(base + (size_t)i * 2 * M_);
        acc.x = fmaf(wv, mv.x, acc.x);
        acc.y = fmaf(wv, mv.y, acc.y);
        acc.z = fmaf(wv, mv.z, acc.z);
        acc.w = fmaf(wv, mv.w, acc.w);
    }
    acc.x += __shfl_xor(acc.x, 32);
    acc.y += __shfl_xor(acc.y, 32);
    acc.z += __shfl_xor(acc.z, 32);
    acc.w += __shfl_xor(acc.w, 32);
    if (lane < 32) acc16[wid][q] = acc;
    __syncthreads();
    if (t < 32) {
        float4 s = acc16[0][t];
        #pragma unroll
        for (int j = 1; j < 16; ++j) {
            float4 u = acc16[j][t];
            s.x += u.x; s.y += u.y; s.z += u.z; s.w += u.w;
        }
        *(float4*)&out_md[b * M_ + t * 4] = s;
    }
}

extern "C" void kernel_launch(void* const* d_in, const int* in_sizes, int n_in,
                              void* d_out, int out_size, void* d_ws, size_t ws_size,
                              hipStream_t stream) {
    const float* emb    = (const float*)d_in[0];
    const float* w_prev = (const float*)d_in[1];
    const float* mem    = (const float*)d_in[2];
    const float* W      = (const float*)d_in[3];
    const float* bias   = (const float*)d_in[4];

    float* out_md = (float*)d_out;               // (512,128) memory_data
    float* out_w  = (float*)d_out + B_ * M_;     // (512,1024) w

    float* ws    = (float*)d_ws;
    float* k_all = ws;                 // 512*128
    float* knorm = ws + 65536;         // 512
    float* scal  = ws + 66048;         // 512*8

    k_params<<<B_, 256, 0, stream>>>(emb, W, bias, k_all, knorm, scal);
    k_fused <<<B_, 1024, 0, stream>>>(mem, w_prev, k_all, knorm, scal, out_md, out_w);
}

// Round 6
// 406.703 us; speedup vs baseline: 1.1017x; 1.0506x over previous
//
#include <hip/hip_runtime.h>
#include <hip/hip_bf16.h>

#define B_ 512
#define E_ 1024
#define N_ 1024
#define M_ 128
#define P_ 134   // M+6

#define RLO 24   // pass-1 iters [24,32): register cache (8 float4/thread)
#define LLO 18   // pass-1 iters [18,24): LDS cache (6 x 16KB = 96KB)

__device__ __forceinline__ float softplus_f(float x) {
    return fmaxf(x, 0.f) + log1pf(expf(-fabsf(x)));
}

// Fully fused NTM read head: one block per batch row b (1024 thr = 16 waves).
// Phase A: params = emb[b] @ W + bias (E split 4-ways, LDS combine) -> k, scalars in LDS.
// Pass 1 : z[n] = beta*cos(k, mem[b,n]) streaming mem[b] (tail cached: regs+LDS).
// Phase B: softmax/gate/shift/pow/renorm entirely in LDS.
// Pass 2 : out_md = sum_n w[n]*mem[b,n,:] (regs + LDS cache + reverse-order L3 re-read).
// ~119 KB LDS -> 1 block/CU: GPU-resident fresh set 256x512KB = 128MB < 256MB L3.
__global__ __launch_bounds__(1024) void k_fused(
    const float* __restrict__ emb, const float* __restrict__ W,
    const float* __restrict__ bias, const float* __restrict__ w_prev,
    const float* __restrict__ mem,
    float* __restrict__ out_md, float* __restrict__ out_w)
{
    __shared__ float se[E_];             // emb row
    __shared__ float partial[4][136];    // E-split partial dots
    __shared__ float sp[136];            // params row (k | beta,g,s0..2,y raw)
    __shared__ float sscal[8];           // beta,g,s0,s1,s2,y,knorm
    __shared__ float zbuf[N_];           // z, later final w
    __shared__ float wgbuf[N_];          // gated weights (neighbor access)
    __shared__ float red[16];
    __shared__ float4 acc16[16][32];
    __shared__ float cache[6][32][M_];   // 96 KB tile cache

    const int b    = blockIdx.x;
    const int t    = threadIdx.x;
    const int wid  = t >> 6;
    const int lane = t & 63;
    const int half = lane >> 5, q = lane & 31;

    // ---- phase A: params = emb[b] @ W + bias ----
    for (int i = t; i < E_; i += 1024) se[i] = emb[b * E_ + i];
    __syncthreads();
    if (t < 536) {
        const int seg = t / 134;          // 0..3 (256 e's each)
        const int col = t - seg * 134;    // 0..133
        const int e0 = seg * 256;
        const float* wcol = W + col;
        float a0 = 0.f, a1 = 0.f, a2 = 0.f, a3 = 0.f;
        #pragma unroll 4
        for (int e = 0; e < 256; e += 4) {
            a0 = fmaf(se[e0 + e + 0], wcol[(size_t)(e0 + e + 0) * P_], a0);
            a1 = fmaf(se[e0 + e + 1], wcol[(size_t)(e0 + e + 1) * P_], a1);
            a2 = fmaf(se[e0 + e + 2], wcol[(size_t)(e0 + e + 2) * P_], a2);
            a3 = fmaf(se[e0 + e + 3], wcol[(size_t)(e0 + e + 3) * P_], a3);
        }
        partial[seg][col] = (a0 + a1) + (a2 + a3);
    }
    __syncthreads();
    if (t < P_)
        sp[t] = bias[t] + ((partial[0][t] + partial[1][t]) + (partial[2][t] + partial[3][t]));
    __syncthreads();
    if (t < 64) {                        // ||k|| (wave 0)
        float v = sp[t] * sp[t] + sp[t + 64] * sp[t + 64];
        #pragma unroll
        for (int m = 1; m < 64; m <<= 1) v += __shfl_xor(v, m);
        if (t == 0) sscal[6] = sqrtf(v);
    }
    if (t == 64) {                       // scalar params (wave 1, overlaps)
        sscal[0] = softplus_f(sp[M_ + 0]);
        sscal[1] = 1.f / (1.f + expf(-sp[M_ + 1]));
        float a0 = sp[M_ + 2], a1 = sp[M_ + 3], a2 = sp[M_ + 4];
        float mx = fmaxf(a0, fmaxf(a1, a2));
        float e0 = expf(a0 - mx), e1 = expf(a1 - mx), e2 = expf(a2 - mx);
        float inv = 1.f / (e0 + e1 + e2);
        sscal[2] = e0 * inv; sscal[3] = e1 * inv; sscal[4] = e2 * inv;
        sscal[5] = 1.f + softplus_f(sp[M_ + 5]);
    }
    __syncthreads();

    const float4 k4   = *(const float4*)&sp[q * 4];
    const float  kn   = sscal[6];
    const float  beta = sscal[0];
    const float  g    = sscal[1];
    const float  s0   = sscal[2];
    const float  s1   = sscal[3];
    const float  s2   = sscal[4];
    const float  y    = sscal[5];

    const float* base = mem + ((size_t)b * N_ + wid * 64 + half) * M_ + q * 4;
    float4 rc[8];

    // ---- pass 1a: stream iters 0..17 ----
    #pragma unroll 6
    for (int i = 0; i < LLO; ++i) {
        const float4 v = *(const float4*)(base + (size_t)i * 2 * M_);
        float dot = v.x * k4.x + v.y * k4.y + v.z * k4.z + v.w * k4.w;
        float sq  = v.x * v.x + v.y * v.y + v.z * v.z + v.w * v.w;
        #pragma unroll
        for (int m = 1; m < 32; m <<= 1) {
            dot += __shfl_xor(dot, m);
            sq  += __shfl_xor(sq,  m);
        }
        if (q == 0)
            zbuf[wid * 64 + 2 * i + half] = beta * dot / (kn * sqrtf(sq) + 1e-16f);
    }
    // ---- pass 1b: iters 18..23, LDS-cached ----
    #pragma unroll
    for (int i = LLO; i < RLO; ++i) {
        const float4 v = *(const float4*)(base + (size_t)i * 2 * M_);
        *(float4*)&cache[i - LLO][wid * 2 + half][q * 4] = v;
        float dot = v.x * k4.x + v.y * k4.y + v.z * k4.z + v.w * k4.w;
        float sq  = v.x * v.x + v.y * v.y + v.z * v.z + v.w * v.w;
        #pragma unroll
        for (int m = 1; m < 32; m <<= 1) {
            dot += __shfl_xor(dot, m);
            sq  += __shfl_xor(sq,  m);
        }
        if (q == 0)
            zbuf[wid * 64 + 2 * i + half] = beta * dot / (kn * sqrtf(sq) + 1e-16f);
    }
    // ---- pass 1c: iters 24..31, register-cached (static indices) ----
    #pragma unroll
    for (int ii = 0; ii < 8; ++ii) {
        const int i = RLO + ii;
        const float4 v = *(const float4*)(base + (size_t)i * 2 * M_);
        rc[ii] = v;
        float dot = v.x * k4.x + v.y * k4.y + v.z * k4.z + v.w * k4.w;
        float sq  = v.x * v.x + v.y * v.y + v.z * v.z + v.w * v.w;
        #pragma unroll
        for (int m = 1; m < 32; m <<= 1) {
            dot += __shfl_xor(dot, m);
            sq  += __shfl_xor(sq,  m);
        }
        if (q == 0)
            zbuf[wid * 64 + 2 * i + half] = beta * dot / (kn * sqrtf(sq) + 1e-16f);
    }
    __syncthreads();

    // ---- phase B: softmax over N + gate + shift + pow + renorm ----
    float zv = zbuf[t];
    float v = zv;
    #pragma unroll
    for (int m = 1; m < 64; m <<= 1) v = fmaxf(v, __shfl_xor(v, m));
    if (lane == 0) red[wid] = v;
    __syncthreads();
    float mx = red[0];
    #pragma unroll
    for (int j = 1; j < 16; ++j) mx = fmaxf(mx, red[j]);
    float ev = expf(zv - mx);
    v = ev;
    #pragma unroll
    for (int m = 1; m < 64; m <<= 1) v += __shfl_xor(v, m);
    __syncthreads();
    if (lane == 0) red[wid] = v;
    __syncthreads();
    float esum = 0.f;
    #pragma unroll
    for (int j = 0; j < 16; ++j) esum += red[j];
    float wc = ev / esum;
    wgbuf[t] = g * wc + (1.f - g) * w_prev[b * N_ + t];
    __syncthreads();
    float wt = s0 * wgbuf[(t - 1) & (N_ - 1)] + s1 * wgbuf[t] + s2 * wgbuf[(t + 1) & (N_ - 1)];
    float wp = powf(wt + 1e-16f, y);
    v = wp;
    #pragma unroll
    for (int m = 1; m < 64; m <<= 1) v += __shfl_xor(v, m);
    __syncthreads();
    if (lane == 0) red[wid] = v;
    __syncthreads();
    float psum = 0.f;
    #pragma unroll
    for (int j = 0; j < 16; ++j) psum += red[j];
    float wfin = wp / psum;
    zbuf[t] = wfin;                       // zbuf now holds final w
    out_w[b * N_ + t] = wfin;
    __syncthreads();

    // ---- pass 2: out_md[b,:] = sum_n w[n] * mem[b,n,:] ----
    float4 acc = make_float4(0.f, 0.f, 0.f, 0.f);
    #pragma unroll
    for (int ii = 7; ii >= 0; --ii) {             // register-cached iters
        float wv = zbuf[wid * 64 + 2 * (RLO + ii) + half];
        acc.x = fmaf(wv, rc[ii].x, acc.x);
        acc.y = fmaf(wv, rc[ii].y, acc.y);
        acc.z = fmaf(wv, rc[ii].z, acc.z);
        acc.w = fmaf(wv, rc[ii].w, acc.w);
    }
    #pragma unroll
    for (int i = RLO - 1; i >= LLO; --i) {        // LDS-cached iters
        float wv = zbuf[wid * 64 + 2 * i + half];
        const float4 mv = *(const float4*)&cache[i - LLO][wid * 2 + half][q * 4];
        acc.x = fmaf(wv, mv.x, acc.x);
        acc.y = fmaf(wv, mv.y, acc.y);
        acc.z = fmaf(wv, mv.z, acc.z);
        acc.w = fmaf(wv, mv.w, acc.w);
    }
    #pragma unroll 6
    for (int i = LLO - 1; i >= 0; --i) {          // re-read (L3-resident, LRU-hot first)
        float wv = zbuf[wid * 64 + 2 * i + half];
        const float4 mv = *(const float4*)(base + (size_t)i * 2 * M_);
        acc.x = fmaf(wv, mv.x, acc.x);
        acc.y = fmaf(wv, mv.y, acc.y);
        acc.z = fmaf(wv, mv.z, acc.z);
        acc.w = fmaf(wv, mv.w, acc.w);
    }
    acc.x += __shfl_xor(acc.x, 32);
    acc.y += __shfl_xor(acc.y, 32);
    acc.z += __shfl_xor(acc.z, 32);
    acc.w += __shfl_xor(acc.w, 32);
    if (lane < 32) acc16[wid][q] = acc;
    __syncthreads();
    if (t < 32) {
        float4 s = acc16[0][t];
        #pragma unroll
        for (int j = 1; j < 16; ++j) {
            float4 u = acc16[j][t];
            s.x += u.x; s.y += u.y; s.z += u.z; s.w += u.w;
        }
        *(float4*)&out_md[b * M_ + t * 4] = s;
    }
}

extern "C" void kernel_launch(void* const* d_in, const int* in_sizes, int n_in,
                              void* d_out, int out_size, void* d_ws, size_t ws_size,
                              hipStream_t stream) {
    const float* emb    = (const float*)d_in[0];
    const float* w_prev = (const float*)d_in[1];
    const float* mem    = (const float*)d_in[2];
    const float* W      = (const float*)d_in[3];
    const float* bias   = (const float*)d_in[4];

    float* out_md = (float*)d_out;               // (512,128) memory_data
    float* out_w  = (float*)d_out + B_ * M_;     // (512,1024) w

    k_fused<<<B_, 1024, 0, stream>>>(emb, W, bias, w_prev, mem, out_md, out_w);
}